// Round 7
// baseline (611.820 us; speedup 1.0000x reference)
//
#include <hip/hip_runtime.h>
#include <hip/hip_fp16.h>

#define BB 16
#define NQ 2048
#define NK 2048
#define DH 128

typedef __attribute__((ext_vector_type(4))) float f32x4;
typedef _Float16 f16x2 __attribute__((ext_vector_type(2)));
typedef _Float16 f16x8 __attribute__((ext_vector_type(8)));
typedef unsigned int u32x2 __attribute__((ext_vector_type(2)));
typedef unsigned int u32x4 __attribute__((ext_vector_type(4)));

#define TWO_PI_F 6.283185307179586f
#define INV2PW2  0.8105694691387023f   /* 8/pi^2 = 1/(2*(pi/4)^2) */
#define QK_SCALE 0.08838834764831845f  /* 1/sqrt(128) */

// RTZ pack (hot loop only — P stash, error irrelevant there).
// NB: cvt_pkrtz returns an __fp16 ext-vector — bit_cast it directly, never
// materialize a _Float16-vector from it (round-5 compile error).
static __device__ __forceinline__ unsigned pkrtz(float a, float b){
  return __builtin_bit_cast(unsigned, __builtin_amdgcn_cvt_pkrtz(a, b));   // lo = a, hi = b
}
// RNE pack (input conversions — keeps QK/PV numerics tight)
static __device__ __forceinline__ unsigned pk_rne(float a, float b){
  f16x2 h = { (_Float16)a, (_Float16)b };
  return __builtin_bit_cast(unsigned, h);
}
static __device__ __forceinline__ f16x8 mk8(unsigned a, unsigned b, unsigned c, unsigned d){
  u32x4 u = {a, b, c, d};
  return __builtin_bit_cast(f16x8, u);
}

// ---------------- K fp32 -> fp16 (RNE) ----------------
__global__ void prep_k16_kernel(const float* __restrict__ K, unsigned short* __restrict__ K16){
  const long NV = (long)BB * NK * DH / 4;
  long stride = (long)gridDim.x * blockDim.x;
  for (long i = (long)blockIdx.x * blockDim.x + threadIdx.x; i < NV; i += stride){
    f32x4 v = ((const f32x4*)K)[i];
    u32x2 o = { pk_rne(v[0], v[1]), pk_rne(v[2], v[3]) };
    ((u32x2*)K16)[i] = o;
  }
}

// ---------------- gate table: gt[k] = exp(-d^2*8/pi^2) / sqrt(DH) ----------------
__global__ void gate_kernel(const float* __restrict__ ph, float* __restrict__ gt){
  int i = blockIdx.x * blockDim.x + threadIdx.x;
  if (i < NK){
    float p = ph[i];
    float d = fminf(p, TWO_PI_F - p);            // CURRENT_PHASE = 0
    gt[i] = expf(-d * d * INV2PW2) * QK_SCALE;
  }
}

// ---------------- V [B][NK][DH] fp32 -> Vt [B][DH][NK] fp16 (RNE) ----------------
__global__ void transpose_v_kernel(const float* __restrict__ V, unsigned short* __restrict__ Vt){
  __shared__ float tile[64][65];
  int b  = blockIdx.z;
  int kb = blockIdx.x * 64;
  int nb = blockIdx.y * 64;
  int t  = threadIdx.x;
  int c = t & 63, rq = t >> 6;
  #pragma unroll
  for (int r = 0; r < 16; ++r){
    int row = rq * 16 + r;
    tile[row][c] = V[((long)b * NK + kb + row) * DH + nb + c];
  }
  __syncthreads();
  #pragma unroll
  for (int r = 0; r < 16; ++r){
    int nrow = rq * 16 + r;
    _Float16 h = (_Float16)tile[c][nrow];
    Vt[((long)b * DH + nb + nrow) * NK + kb + c] = __builtin_bit_cast(unsigned short, h);
  }
}

// ---------------- fused attention ----------------
// One workgroup = (b, 16 q-rows). 4 waves, wave w owns keys [512w, 512w+512).
// QK MFMA swapped (A=K, B=Q) -> lane(lg,ll) acc[r] = S[key kk+4lg+r][q=ll].
// exp values kept in regs (packed fp16); shuffled into PV A-fragments;
// lsum reduced in LDS; P written ONCE normalized; O reduced in LDS.
__global__ __launch_bounds__(256) void fused_attn_kernel(
      const float* __restrict__ Q, const unsigned short* __restrict__ K16,
      const unsigned short* __restrict__ Vt, const float* __restrict__ gt,
      float* __restrict__ O, float* __restrict__ P){
  int wg = blockIdx.x;
  int swz = (wg & 7) * 256 + (wg >> 3);   // XCD-contiguous swizzle (2048 = 8*256, bijective)
  int b  = swz >> 7;
  int qb = (swz & 127) << 4;
  int tid = threadIdx.x, wave = tid >> 6, lane = tid & 63;
  int lg = lane >> 4, ll = lane & 15;

  // Q fragments (fp16 RNE, B operand): lane holds Q[qb+ll][ks*32 + lg*8 + e]
  f16x8 qf[4];
  const float* qrow = Q + ((long)b * NQ + qb + ll) * DH + lg * 8;
  #pragma unroll
  for (int ks = 0; ks < 4; ++ks){
    f32x4 lo = *(const f32x4*)(qrow + ks * 32);
    f32x4 hi = *(const f32x4*)(qrow + ks * 32 + 4);
    qf[ks] = mk8(pk_rne(lo[0],lo[1]), pk_rne(lo[2],lo[3]), pk_rne(hi[0],hi[1]), pk_rne(hi[2],hi[3]));
  }

  const _Float16* Kb = (const _Float16*)K16 + (long)b * NK * DH;
  const _Float16* Vb = (const _Float16*)Vt  + (long)b * DH * NK;

  f32x4 oacc[8];
  #pragma unroll
  for (int i = 0; i < 8; ++i) oacc[i] = (f32x4){0.f, 0.f, 0.f, 0.f};
  float rs = 0.f;
  unsigned stw0[16], stw1[16], stx0[16], stx1[16];   // packed fp16 exp stash (reg-resident)

  #pragma unroll
  for (int sl = 0; sl < 16; ++sl){
    int kk = wave * 512 + sl * 32;
    unsigned w0, w1, x0, x1;
    // ---- step 0: keys kk .. kk+15 ----
    {
      const _Float16* krow = Kb + (long)(kk + ll) * DH + lg * 8;
      f32x4 acc = {0.f, 0.f, 0.f, 0.f};
      #pragma unroll
      for (int ks = 0; ks < 4; ++ks)
        acc = __builtin_amdgcn_mfma_f32_16x16x32_f16(*(const f16x8*)(krow + ks*32), qf[ks], acc, 0, 0, 0);
      f32x4 g = *(const f32x4*)(gt + kk + lg * 4);
      float e0 = __expf(acc[0]*g[0]), e1 = __expf(acc[1]*g[1]);
      float e2 = __expf(acc[2]*g[2]), e3 = __expf(acc[3]*g[3]);
      rs += (e0 + e1) + (e2 + e3);
      w0 = pkrtz(e0, e1); w1 = pkrtz(e2, e3);
    }
    // ---- step 1: keys kk+16 .. kk+31 ----
    {
      const _Float16* krow = Kb + (long)(kk + 16 + ll) * DH + lg * 8;
      f32x4 acc = {0.f, 0.f, 0.f, 0.f};
      #pragma unroll
      for (int ks = 0; ks < 4; ++ks)
        acc = __builtin_amdgcn_mfma_f32_16x16x32_f16(*(const f16x8*)(krow + ks*32), qf[ks], acc, 0, 0, 0);
      f32x4 g = *(const f32x4*)(gt + kk + 16 + lg * 4);
      float e0 = __expf(acc[0]*g[0]), e1 = __expf(acc[1]*g[1]);
      float e2 = __expf(acc[2]*g[2]), e3 = __expf(acc[3]*g[3]);
      rs += (e0 + e1) + (e2 + e3);
      x0 = pkrtz(e0, e1); x1 = pkrtz(e2, e3);
    }
    stw0[sl] = w0; stw1[sl] = w1; stx0[sl] = x0; stx1[sl] = x1;

    // ---- build PV A-fragment: lane(lg,ll) needs P[q=ll][kk + 8lg + 0..7] ----
    // lane(lg,ll) holds w: k-local 4lg..4lg+3 (step0), x: 16+4lg.. (step1).
    // shfl_xor16 pairs lg0<->1, lg2<->3; then xor32 routes pair-groups.
    unsigned shw0 = __shfl_xor(w0, 16), shw1 = __shfl_xor(w1, 16);
    unsigned shx0 = __shfl_xor(x0, 16), shx1 = __shfl_xor(x1, 16);
    bool odd = (lg & 1);
    // Wc = k-ascending combo of this lg-pair's w: pair{0,1}->k0..7, pair{2,3}->k8..15
    unsigned Wc0 = odd ? shw0 : w0, Wc1 = odd ? shw1 : w1;
    unsigned Wc2 = odd ? w0 : shw0, Wc3 = odd ? w1 : shw1;
    unsigned Xc0 = odd ? shx0 : x0, Xc1 = odd ? shx1 : x1;
    unsigned Xc2 = odd ? x0 : shx0, Xc3 = odd ? x1 : shx1;
    // partner (lane^32) wants: lg2/3 send Wc (to lg1), lg0/1 send Xc (to lg2)
    unsigned Z0 = (lg & 2) ? Wc0 : Xc0, Z1 = (lg & 2) ? Wc1 : Xc1;
    unsigned Z2 = (lg & 2) ? Wc2 : Xc2, Z3 = (lg & 2) ? Wc3 : Xc3;
    unsigned S0 = __shfl_xor(Z0, 32), S1 = __shfl_xor(Z1, 32);
    unsigned S2 = __shfl_xor(Z2, 32), S3 = __shfl_xor(Z3, 32);
    // final: lg0 -> own Wc (k0..7); lg1 -> S (=lg3.Wc, k8..15); lg2 -> S (=lg0.Xc, k16..23); lg3 -> own Xc (k24..31)
    unsigned A0 = (lg == 0) ? Wc0 : (lg == 3) ? Xc0 : S0;
    unsigned A1 = (lg == 0) ? Wc1 : (lg == 3) ? Xc1 : S1;
    unsigned A2 = (lg == 0) ? Wc2 : (lg == 3) ? Xc2 : S2;
    unsigned A3 = (lg == 0) ? Wc3 : (lg == 3) ? Xc3 : S3;
    f16x8 af = mk8(A0, A1, A2, A3);

    // ---- PV: oacc[nt] += P-tile x V[kk..kk+31][nt*16..+15] ----
    #pragma unroll
    for (int nt = 0; nt < 8; ++nt){
      f16x8 bv = *(const f16x8*)(Vb + (long)(nt * 16 + ll) * NK + kk + lg * 8);
      oacc[nt] = __builtin_amdgcn_mfma_f32_16x16x32_f16(af, bv, oacc[nt], 0, 0, 0);
    }
  }

  // ---- row sums: lanes sharing ll cover this wave's 512 keys ----
  rs += __shfl_xor(rs, 16);
  rs += __shfl_xor(rs, 32);
  __shared__ float sums[4][16];
  __shared__ float ltot[16];
  __shared__ float olds[4][16][128];
  if (lane < 16) sums[wave][lane] = rs;
  #pragma unroll
  for (int nt = 0; nt < 8; ++nt)
    #pragma unroll
    for (int r = 0; r < 4; ++r)
      olds[wave][lg * 4 + r][nt * 16 + ll] = oacc[nt][r];
  __syncthreads();
  if (tid < 16) ltot[tid] = (sums[0][tid] + sums[1][tid]) + (sums[2][tid] + sums[3][tid]);
  __syncthreads();

  // ---- O = (sum over waves) / ltot ----
  float* Ob = O + ((long)b * NQ + qb) * DH;
  int base = tid * 8;
  #pragma unroll
  for (int c = 0; c < 8; c += 4){
    f32x4 o;
    #pragma unroll
    for (int j = 0; j < 4; ++j){
      int idx = base + c + j;
      int m = idx >> 7, n = idx & 127;
      o[j] = ((olds[0][m][n] + olds[1][m][n]) + (olds[2][m][n] + olds[3][m][n])) / ltot[m];
    }
    *(f32x4*)(Ob + base + c) = o;
  }

  // ---- attention write: each lane writes exactly what it computed, normalized ----
  float inv = 1.0f / ltot[ll];
  float* Prow = P + ((long)b * NQ + qb + ll) * NK;
  #pragma unroll
  for (int sl = 0; sl < 16; ++sl){
    int kk = wave * 512 + sl * 32;
    f16x2 h0 = __builtin_bit_cast(f16x2, stw0[sl]);
    f16x2 h1 = __builtin_bit_cast(f16x2, stw1[sl]);
    f32x4 v0 = { (float)h0[0] * inv, (float)h0[1] * inv, (float)h1[0] * inv, (float)h1[1] * inv };
    *(f32x4*)(Prow + kk + lg * 4) = v0;
    f16x2 h2 = __builtin_bit_cast(f16x2, stx0[sl]);
    f16x2 h3 = __builtin_bit_cast(f16x2, stx1[sl]);
    f32x4 v1 = { (float)h2[0] * inv, (float)h2[1] * inv, (float)h3[0] * inv, (float)h3[1] * inv };
    *(f32x4*)(Prow + kk + 16 + lg * 4) = v1;
  }
}

extern "C" void kernel_launch(void* const* d_in, const int* in_sizes, int n_in,
                              void* d_out, int out_size, void* d_ws, size_t ws_size,
                              hipStream_t stream){
  const float* Q  = (const float*)d_in[0];
  const float* K  = (const float*)d_in[1];
  const float* V  = (const float*)d_in[2];
  const float* ph = (const float*)d_in[3];

  float* O = (float*)d_out;                         // [16,2048,128]
  float* P = O + (long)BB * NQ * DH;                // attention [16,2048,2048]

  unsigned short* K16 = (unsigned short*)d_ws;      // 8.39 MB fp16
  unsigned short* Vt  = K16 + (long)BB * NK * DH;   // 8.39 MB fp16, [B][DH][NK]
  float* gt = (float*)(Vt + (long)BB * DH * NK);    // 8 KB

  hipLaunchKernelGGL(prep_k16_kernel,    dim3(1024),      dim3(256), 0, stream, K, K16);
  hipLaunchKernelGGL(gate_kernel,        dim3(8),         dim3(256), 0, stream, ph, gt);
  hipLaunchKernelGGL(transpose_v_kernel, dim3(32, 2, BB), dim3(256), 0, stream, V, Vt);
  hipLaunchKernelGGL(fused_attn_kernel,  dim3(2048),      dim3(256), 0, stream, Q, K16, Vt, gt, O, P);
}